// Round 1
// 371.741 us; speedup vs baseline: 1.4568x; 1.4568x over previous
//
#include <hip/hip_runtime.h>

// Problem constants (from reference)
#define NUM_NODES 100000
#define MAX_DEGREE 128
#define NODE_DIM 256
#define VERT_NUM 16384
#define NUM_SAMPLES 32
#define SENTINEL (NUM_NODES - 1)

#define VPB 16                   // vertices per block
#define NBLK (VERT_NUM / VPB)    // 1024 blocks

// Output layout (FLOAT32 elements), concatenated in reference return order:
// adj_out [V*S] | att_lists [V*S] | adj_lists_numnz [V] | out_mean [V]
#define ADJ_OFF 0
#define ATT_OFF (VERT_NUM * NUM_SAMPLES)
#define NNZ_OFF (2 * VERT_NUM * NUM_SAMPLES)
#define MEAN_OFF (2 * VERT_NUM * NUM_SAMPLES + VERT_NUM)

__device__ __forceinline__ float bfbits2f(unsigned int bits16) {
    return __uint_as_float(bits16 << 16);
}

// Probe: is float storage f32 (1) or packed bf16 (0)?
__device__ __forceinline__ int probe_isf32(const void* p) {
    const unsigned int* fu = (const unsigned int*)p;
    int cnt = 0;
    for (int i = 0; i < 64; ++i) {
        const unsigned int w = fu[i];
        const unsigned int e2 = (w >> 7) & 0xFFu;
        if (e2 >= 90u && e2 <= 140u && (w & 0xFFFFu) != 0u) ++cnt;
    }
    return (cnt >= 40) ? 0 : 1;
}

// Templated loads: no per-element select, vectorized when f32.
template <int ISF32>
__device__ __forceinline__ float ld1(const void* p, size_t idx) {
    if (ISF32) return ((const float*)p)[idx];
    return bfbits2f(((const unsigned short*)p)[idx]);
}

template <int ISF32>
__device__ __forceinline__ float4 load4(const void* p, size_t idx) {
    if (ISF32) {
        return *(const float4*)((const float*)p + idx);
    } else {
        const ushort4 u = *(const ushort4*)((const unsigned short*)p + idx);
        float4 v;
        v.x = bfbits2f(u.x); v.y = bfbits2f(u.y);
        v.z = bfbits2f(u.z); v.w = bfbits2f(u.w);
        return v;
    }
}

// ---------------------------------------------------------------------------
// Fused kernel body. fp64 accumulation of exact f32 products, f32
// materialization at each tensor boundary (l, out) — matches reference
// bit-exactly independent of summation order (29 spare mantissa bits).
// ---------------------------------------------------------------------------
template <int ISF32>
__device__ __forceinline__ void body(
    const int* __restrict__ adj_info,
    const void* __restrict__ features,
    const void* __restrict__ W,
    const void* __restrict__ bias,
    float* __restrict__ out,
    float (*A_s)[NODE_DIM + 4],
    float (*L_s)[NODE_DIM + 4],
    const int* s_ids,
    const int* s_ur,
    int (*s_adj)[NUM_SAMPLES],
    float (*s_out)[NUM_SAMPLES],
    int tid, int v0)
{
    // ---- stage gathered feature rows into LDS as f32 (coalesced float4) ----
    #pragma unroll
    for (int i = 0; i < 4; ++i) {
        const int idx = tid + i * 256;   // 0..1023
        const int r = idx >> 6;          // 0..15 (uniform per wave)
        const int cg = (idx & 63) * 4;   // 0..252
        const float4 v = load4<ISF32>(features, (size_t)s_ids[r] * NODE_DIM + cg);
        *(float4*)&A_s[r][cg] = v;
    }
    // gather adj samples
    #pragma unroll
    for (int i = 0; i < 2; ++i) {
        const int e = tid * 2 + i;       // 0..511
        const int r = e >> 5;
        const int s = e & 31;
        s_adj[r][s] = adj_info[(size_t)s_ids[r] * MAX_DEGREE + s_ur[s]];
    }
    __syncthreads();

    // ---- l = A@W + b; thread = output column, fp64 accumulate ----
    {
        const int col = tid;
        double acc[VPB];
        #pragma unroll
        for (int g = 0; g < VPB; ++g) acc[g] = 0.0;
        for (int k = 0; k < NODE_DIM; k += 4) {
            const double w0 = (double)ld1<ISF32>(W, (size_t)(k + 0) * NODE_DIM + col);
            const double w1 = (double)ld1<ISF32>(W, (size_t)(k + 1) * NODE_DIM + col);
            const double w2 = (double)ld1<ISF32>(W, (size_t)(k + 2) * NODE_DIM + col);
            const double w3 = (double)ld1<ISF32>(W, (size_t)(k + 3) * NODE_DIM + col);
            #pragma unroll
            for (int g = 0; g < VPB; ++g) {
                const float4 a = *(const float4*)&A_s[g][k];
                acc[g] = fma((double)a.x, w0, acc[g]);
                acc[g] = fma((double)a.y, w1, acc[g]);
                acc[g] = fma((double)a.z, w2, acc[g]);
                acc[g] = fma((double)a.w, w3, acc[g]);
            }
        }
        const double bv = (double)ld1<ISF32>(bias, col);
        #pragma unroll
        for (int g = 0; g < VPB; ++g) L_s[g][col] = (float)(acc[g] + bv);
    }
    __syncthreads();

    // ---- einsum: 16-lane group per vertex, coalesced float4 row loads ----
    // Group q = tid>>4 owns vertex q. Lane ln covers cols {j*64 + ln*4 .. +3}.
    {
        const int q = tid >> 4;
        const int ln = tid & 15;
        const float4 Lv0 = *(const float4*)&L_s[q][  0 + ln * 4];
        const float4 Lv1 = *(const float4*)&L_s[q][ 64 + ln * 4];
        const float4 Lv2 = *(const float4*)&L_s[q][128 + ln * 4];
        const float4 Lv3 = *(const float4*)&L_s[q][192 + ln * 4];
        #pragma unroll 2
        for (int s = 0; s < NUM_SAMPLES; ++s) {
            const size_t base = (size_t)s_adj[q][s] * NODE_DIM + ln * 4;
            const float4 f0 = load4<ISF32>(features, base +   0);
            const float4 f1 = load4<ISF32>(features, base +  64);
            const float4 f2 = load4<ISF32>(features, base + 128);
            const float4 f3 = load4<ISF32>(features, base + 192);
            double a = 0.0;
            a = fma((double)f0.x, (double)Lv0.x, a);
            a = fma((double)f0.y, (double)Lv0.y, a);
            a = fma((double)f0.z, (double)Lv0.z, a);
            a = fma((double)f0.w, (double)Lv0.w, a);
            a = fma((double)f1.x, (double)Lv1.x, a);
            a = fma((double)f1.y, (double)Lv1.y, a);
            a = fma((double)f1.z, (double)Lv1.z, a);
            a = fma((double)f1.w, (double)Lv1.w, a);
            a = fma((double)f2.x, (double)Lv2.x, a);
            a = fma((double)f2.y, (double)Lv2.y, a);
            a = fma((double)f2.z, (double)Lv2.z, a);
            a = fma((double)f2.w, (double)Lv2.w, a);
            a = fma((double)f3.x, (double)Lv3.x, a);
            a = fma((double)f3.y, (double)Lv3.y, a);
            a = fma((double)f3.z, (double)Lv3.z, a);
            a = fma((double)f3.w, (double)Lv3.w, a);
            // 16-lane tree reduce (fp64; order-insensitive at f32 boundary)
            a += __shfl_xor(a, 8);
            a += __shfl_xor(a, 4);
            a += __shfl_xor(a, 2);
            a += __shfl_xor(a, 1);
            if (ln == 0) s_out[q][s] = (float)a;   // f32 materialization
        }
    }
    __syncthreads();

    // ---- epilogue: 16 lanes per vertex, 2 samples per lane ----
    {
        const int q = tid >> 4;
        const int ln = tid & 15;
        const int v = v0 + q;
        const float o0 = fmaxf(s_out[q][ln], 0.0f);
        const float o1 = fmaxf(s_out[q][ln + 16], 0.0f);
        double ss = (double)o0 + (double)o1;
        ss += __shfl_xor(ss, 8);
        ss += __shfl_xor(ss, 4);
        ss += __shfl_xor(ss, 2);
        ss += __shfl_xor(ss, 1);
        const float mean = (float)(ss * (1.0 / 32.0));
        const float thr = 0.5f * mean;
        const int n0 = s_adj[q][ln];
        const int n1 = s_adj[q][ln + 16];
        const bool c0 = (n0 == SENTINEL) || (o0 > thr);
        const bool c1 = (n1 == SENTINEL) || (o1 > thr);
        const size_t ob = (size_t)v * NUM_SAMPLES;
        out[ADJ_OFF + ob + ln]      = c0 ? (float)SENTINEL : (float)n0;
        out[ADJ_OFF + ob + ln + 16] = c1 ? (float)SENTINEL : (float)n1;
        out[ATT_OFF + ob + ln]      = 1.0f;
        out[ATT_OFF + ob + ln + 16] = 1.0f;
        int nz = (c0 ? 0 : 1) + (c1 ? 0 : 1);
        nz += __shfl_xor(nz, 8);
        nz += __shfl_xor(nz, 4);
        nz += __shfl_xor(nz, 2);
        nz += __shfl_xor(nz, 1);
        if (ln == 0) {
            out[NNZ_OFF + v] = (float)nz;
            out[MEAN_OFF + v] = mean;
        }
    }
}

__global__ __launch_bounds__(256)
void FastMLNeighborSampler___9337258901923_kernel(
    const int* ids,
    const int* unif_rand,
    const int* adj_info,
    const void* features_raw,
    const void* W_raw,
    const void* bias_raw,
    float* out) {
    __shared__ float A_s[VPB][NODE_DIM + 4];
    __shared__ float L_s[VPB][NODE_DIM + 4];
    __shared__ int s_ids[VPB];
    __shared__ int s_ur[NUM_SAMPLES];
    __shared__ int s_adj[VPB][NUM_SAMPLES];
    __shared__ float s_out[VPB][NUM_SAMPLES];
    __shared__ int s_isf32;

    const int tid = threadIdx.x;
    const int v0 = blockIdx.x * VPB;

    if (tid == 0) s_isf32 = probe_isf32(features_raw);
    if (tid < VPB) {
        s_ids[tid] = ids[v0 + tid];
    } else if (tid < VPB + NUM_SAMPLES) {
        s_ur[tid - VPB] = unif_rand[tid - VPB];
    }
    __syncthreads();

    if (s_isf32) {
        body<1>(adj_info, features_raw, W_raw, bias_raw, out,
                A_s, L_s, s_ids, s_ur, s_adj, s_out, tid, v0);
    } else {
        body<0>(adj_info, features_raw, W_raw, bias_raw, out,
                A_s, L_s, s_ids, s_ur, s_adj, s_out, tid, v0);
    }
}

extern "C" void kernel_launch(void* const* d_in, const int* in_sizes, int n_in,
                              void* d_out, int out_size, void* d_ws, size_t ws_size,
                              hipStream_t stream) {
    const int* ids = nullptr;
    const int* unif_rand = nullptr;
    const int* adj_info = nullptr;
    const void* features = nullptr;
    const void* W = nullptr;
    const void* bias = nullptr;
    for (int i = 0; i < n_in; ++i) {
        switch (in_sizes[i]) {
            case VERT_NUM:               ids       = (const int*)d_in[i]; break;
            case NUM_SAMPLES:            unif_rand = (const int*)d_in[i]; break;
            case NUM_NODES * MAX_DEGREE: adj_info  = (const int*)d_in[i]; break;
            case NUM_NODES * NODE_DIM:   features  = (const void*)d_in[i]; break;
            case NODE_DIM * NODE_DIM:    W         = (const void*)d_in[i]; break;
            case NODE_DIM:               bias      = (const void*)d_in[i]; break;
            default: break;
        }
    }
    if (!ids || !unif_rand || !adj_info || !features || !W || !bias) {
        ids       = (const int*)d_in[0];
        unif_rand = (const int*)d_in[1];
        adj_info  = (const int*)d_in[2];
        features  = (const void*)d_in[3];
        W         = (const void*)d_in[4];
        bias      = (const void*)d_in[5];
    }
    float* out = (float*)d_out;

    FastMLNeighborSampler___9337258901923_kernel<<<NBLK, 256, 0, stream>>>(
        ids, unif_rand, adj_info, features, W, bias, out);
}

// Round 2
// 366.310 us; speedup vs baseline: 1.4784x; 1.0148x over previous
//
#include <hip/hip_runtime.h>

// Problem constants (from reference)
#define NUM_NODES 100000
#define MAX_DEGREE 128
#define NODE_DIM 256
#define VERT_NUM 16384
#define NUM_SAMPLES 32
#define SENTINEL (NUM_NODES - 1)

#define VPB 16                   // vertices per block
#define NBLK (VERT_NUM / VPB)    // 1024 blocks

// Output layout (FLOAT32 elements), concatenated in reference return order:
// adj_out [V*S] | att_lists [V*S] | adj_lists_numnz [V] | out_mean [V]
#define ADJ_OFF 0
#define ATT_OFF (VERT_NUM * NUM_SAMPLES)
#define NNZ_OFF (2 * VERT_NUM * NUM_SAMPLES)
#define MEAN_OFF (2 * VERT_NUM * NUM_SAMPLES + VERT_NUM)

__device__ __forceinline__ float bfbits2f(unsigned int bits16) {
    return __uint_as_float(bits16 << 16);
}

// Probe: is float storage f32 (1) or packed bf16 (0)?
__device__ __forceinline__ int probe_isf32(const void* p) {
    const unsigned int* fu = (const unsigned int*)p;
    int cnt = 0;
    for (int i = 0; i < 64; ++i) {
        const unsigned int w = fu[i];
        const unsigned int e2 = (w >> 7) & 0xFFu;
        if (e2 >= 90u && e2 <= 140u && (w & 0xFFFFu) != 0u) ++cnt;
    }
    return (cnt >= 40) ? 0 : 1;
}

// Templated loads: no per-element select, vectorized when f32.
template <int ISF32>
__device__ __forceinline__ float ld1(const void* p, size_t idx) {
    if (ISF32) return ((const float*)p)[idx];
    return bfbits2f(((const unsigned short*)p)[idx]);
}

template <int ISF32>
__device__ __forceinline__ float4 load4(const void* p, size_t idx) {
    if (ISF32) {
        return *(const float4*)((const float*)p + idx);
    } else {
        const ushort4 u = *(const ushort4*)((const unsigned short*)p + idx);
        float4 v;
        v.x = bfbits2f(u.x); v.y = bfbits2f(u.y);
        v.z = bfbits2f(u.z); v.w = bfbits2f(u.w);
        return v;
    }
}

// ---------------------------------------------------------------------------
// Fused kernel body. fp64 accumulation of exact f32 products, f32
// materialization at each tensor boundary (l, out) — matches reference
// bit-exactly independent of summation order (29 spare mantissa bits).
//
// AL_s is an OVERLAY: holds gathered A rows during the matmul phase, then is
// overwritten (after a barrier) with L = A@W + b for the einsum phase.
// This halves the LDS footprint (37.9 KB -> ~21 KB) => 7 blocks/CU instead
// of 4 => 28 waves/CU for latency hiding.
// ---------------------------------------------------------------------------
template <int ISF32>
__device__ __forceinline__ void body(
    const int* __restrict__ adj_info,
    const void* __restrict__ features,
    const void* __restrict__ W,
    const void* __restrict__ bias,
    float* __restrict__ out,
    float (*AL_s)[NODE_DIM + 4],
    const int* s_ids,
    const int* s_ur,
    int (*s_adj)[NUM_SAMPLES],
    float (*s_out)[NUM_SAMPLES],
    int tid, int v0)
{
    // ---- stage gathered feature rows into LDS as f32 (coalesced float4) ----
    #pragma unroll
    for (int i = 0; i < 4; ++i) {
        const int idx = tid + i * 256;   // 0..1023
        const int r = idx >> 6;          // 0..15 (uniform per wave)
        const int cg = (idx & 63) * 4;   // 0..252
        const float4 v = load4<ISF32>(features, (size_t)s_ids[r] * NODE_DIM + cg);
        *(float4*)&AL_s[r][cg] = v;
    }
    // gather adj samples
    #pragma unroll
    for (int i = 0; i < 2; ++i) {
        const int e = tid * 2 + i;       // 0..511
        const int r = e >> 5;
        const int s = e & 31;
        s_adj[r][s] = adj_info[(size_t)s_ids[r] * MAX_DEGREE + s_ur[s]];
    }
    __syncthreads();

    // ---- l = A@W + b; thread = output column, fp64 accumulate ----
    double acc[VPB];
    {
        const int col = tid;
        #pragma unroll
        for (int g = 0; g < VPB; ++g) acc[g] = 0.0;
        for (int k = 0; k < NODE_DIM; k += 4) {
            const double w0 = (double)ld1<ISF32>(W, (size_t)(k + 0) * NODE_DIM + col);
            const double w1 = (double)ld1<ISF32>(W, (size_t)(k + 1) * NODE_DIM + col);
            const double w2 = (double)ld1<ISF32>(W, (size_t)(k + 2) * NODE_DIM + col);
            const double w3 = (double)ld1<ISF32>(W, (size_t)(k + 3) * NODE_DIM + col);
            #pragma unroll
            for (int g = 0; g < VPB; ++g) {
                const float4 a = *(const float4*)&AL_s[g][k];
                acc[g] = fma((double)a.x, w0, acc[g]);
                acc[g] = fma((double)a.y, w1, acc[g]);
                acc[g] = fma((double)a.z, w2, acc[g]);
                acc[g] = fma((double)a.w, w3, acc[g]);
            }
        }
    }
    // all A reads complete before L overwrites the same buffer
    __syncthreads();
    {
        const int col = tid;
        const double bv = (double)ld1<ISF32>(bias, col);
        #pragma unroll
        for (int g = 0; g < VPB; ++g) AL_s[g][col] = (float)(acc[g] + bv);
    }
    __syncthreads();

    // ---- einsum: 16-lane group per vertex, coalesced float4 row loads ----
    // Group q = tid>>4 owns vertex q. Lane ln covers cols {j*64 + ln*4 .. +3}.
    {
        const int q = tid >> 4;
        const int ln = tid & 15;
        const float4 Lv0 = *(const float4*)&AL_s[q][  0 + ln * 4];
        const float4 Lv1 = *(const float4*)&AL_s[q][ 64 + ln * 4];
        const float4 Lv2 = *(const float4*)&AL_s[q][128 + ln * 4];
        const float4 Lv3 = *(const float4*)&AL_s[q][192 + ln * 4];
        const int* adjq = s_adj[q];
        #pragma unroll 2
        for (int s = 0; s < NUM_SAMPLES; ++s) {
            const size_t base = (size_t)adjq[s] * NODE_DIM + ln * 4;
            const float4 f0 = load4<ISF32>(features, base +   0);
            const float4 f1 = load4<ISF32>(features, base +  64);
            const float4 f2 = load4<ISF32>(features, base + 128);
            const float4 f3 = load4<ISF32>(features, base + 192);
            double a = 0.0;
            a = fma((double)f0.x, (double)Lv0.x, a);
            a = fma((double)f0.y, (double)Lv0.y, a);
            a = fma((double)f0.z, (double)Lv0.z, a);
            a = fma((double)f0.w, (double)Lv0.w, a);
            a = fma((double)f1.x, (double)Lv1.x, a);
            a = fma((double)f1.y, (double)Lv1.y, a);
            a = fma((double)f1.z, (double)Lv1.z, a);
            a = fma((double)f1.w, (double)Lv1.w, a);
            a = fma((double)f2.x, (double)Lv2.x, a);
            a = fma((double)f2.y, (double)Lv2.y, a);
            a = fma((double)f2.z, (double)Lv2.z, a);
            a = fma((double)f2.w, (double)Lv2.w, a);
            a = fma((double)f3.x, (double)Lv3.x, a);
            a = fma((double)f3.y, (double)Lv3.y, a);
            a = fma((double)f3.z, (double)Lv3.z, a);
            a = fma((double)f3.w, (double)Lv3.w, a);
            // 16-lane tree reduce (fp64; order-insensitive at f32 boundary)
            a += __shfl_xor(a, 8);
            a += __shfl_xor(a, 4);
            a += __shfl_xor(a, 2);
            a += __shfl_xor(a, 1);
            if (ln == 0) s_out[q][s] = (float)a;   // f32 materialization
        }
    }
    __syncthreads();

    // ---- epilogue: 16 lanes per vertex, 2 samples per lane ----
    {
        const int q = tid >> 4;
        const int ln = tid & 15;
        const int v = v0 + q;
        const float o0 = fmaxf(s_out[q][ln], 0.0f);
        const float o1 = fmaxf(s_out[q][ln + 16], 0.0f);
        double ss = (double)o0 + (double)o1;
        ss += __shfl_xor(ss, 8);
        ss += __shfl_xor(ss, 4);
        ss += __shfl_xor(ss, 2);
        ss += __shfl_xor(ss, 1);
        const float mean = (float)(ss * (1.0 / 32.0));
        const float thr = 0.5f * mean;
        const int n0 = s_adj[q][ln];
        const int n1 = s_adj[q][ln + 16];
        const bool c0 = (n0 == SENTINEL) || (o0 > thr);
        const bool c1 = (n1 == SENTINEL) || (o1 > thr);
        const size_t ob = (size_t)v * NUM_SAMPLES;
        out[ADJ_OFF + ob + ln]      = c0 ? (float)SENTINEL : (float)n0;
        out[ADJ_OFF + ob + ln + 16] = c1 ? (float)SENTINEL : (float)n1;
        out[ATT_OFF + ob + ln]      = 1.0f;
        out[ATT_OFF + ob + ln + 16] = 1.0f;
        int nz = (c0 ? 0 : 1) + (c1 ? 0 : 1);
        nz += __shfl_xor(nz, 8);
        nz += __shfl_xor(nz, 4);
        nz += __shfl_xor(nz, 2);
        nz += __shfl_xor(nz, 1);
        if (ln == 0) {
            out[NNZ_OFF + v] = (float)nz;
            out[MEAN_OFF + v] = mean;
        }
    }
}

__global__ __launch_bounds__(256, 7)
void FastMLNeighborSampler___9337258901923_kernel(
    const int* ids,
    const int* unif_rand,
    const int* adj_info,
    const void* features_raw,
    const void* W_raw,
    const void* bias_raw,
    float* out) {
    __shared__ float AL_s[VPB][NODE_DIM + 4];   // A-tile, then L-tile (overlay)
    __shared__ int s_ids[VPB];
    __shared__ int s_ur[NUM_SAMPLES];
    __shared__ int s_adj[VPB][NUM_SAMPLES];
    __shared__ float s_out[VPB][NUM_SAMPLES];
    __shared__ int s_isf32;

    const int tid = threadIdx.x;
    const int v0 = blockIdx.x * VPB;

    if (tid == 0) s_isf32 = probe_isf32(features_raw);
    if (tid < VPB) {
        s_ids[tid] = ids[v0 + tid];
    } else if (tid < VPB + NUM_SAMPLES) {
        s_ur[tid - VPB] = unif_rand[tid - VPB];
    }
    __syncthreads();

    if (s_isf32) {
        body<1>(adj_info, features_raw, W_raw, bias_raw, out,
                AL_s, s_ids, s_ur, s_adj, s_out, tid, v0);
    } else {
        body<0>(adj_info, features_raw, W_raw, bias_raw, out,
                AL_s, s_ids, s_ur, s_adj, s_out, tid, v0);
    }
}

extern "C" void kernel_launch(void* const* d_in, const int* in_sizes, int n_in,
                              void* d_out, int out_size, void* d_ws, size_t ws_size,
                              hipStream_t stream) {
    const int* ids = nullptr;
    const int* unif_rand = nullptr;
    const int* adj_info = nullptr;
    const void* features = nullptr;
    const void* W = nullptr;
    const void* bias = nullptr;
    for (int i = 0; i < n_in; ++i) {
        switch (in_sizes[i]) {
            case VERT_NUM:               ids       = (const int*)d_in[i]; break;
            case NUM_SAMPLES:            unif_rand = (const int*)d_in[i]; break;
            case NUM_NODES * MAX_DEGREE: adj_info  = (const int*)d_in[i]; break;
            case NUM_NODES * NODE_DIM:   features  = (const void*)d_in[i]; break;
            case NODE_DIM * NODE_DIM:    W         = (const void*)d_in[i]; break;
            case NODE_DIM:               bias      = (const void*)d_in[i]; break;
            default: break;
        }
    }
    if (!ids || !unif_rand || !adj_info || !features || !W || !bias) {
        ids       = (const int*)d_in[0];
        unif_rand = (const int*)d_in[1];
        adj_info  = (const int*)d_in[2];
        features  = (const void*)d_in[3];
        W         = (const void*)d_in[4];
        bias      = (const void*)d_in[5];
    }
    float* out = (float*)d_out;

    FastMLNeighborSampler___9337258901923_kernel<<<NBLK, 256, 0, stream>>>(
        ids, unif_rand, adj_info, features, W, bias, out);
}

// Round 3
// 347.864 us; speedup vs baseline: 1.5568x; 1.0530x over previous
//
#include <hip/hip_runtime.h>

// Problem constants (from reference)
#define NUM_NODES 100000
#define MAX_DEGREE 128
#define NODE_DIM 256
#define VERT_NUM 16384
#define NUM_SAMPLES 32
#define SENTINEL (NUM_NODES - 1)

#define VPB 8                    // vertices per block (R3: halved for 2x grid)
#define NBLK (VERT_NUM / VPB)    // 2048 blocks = 8 blocks/CU on 256 CUs

// Output layout (FLOAT32 elements), concatenated in reference return order:
// adj_out [V*S] | att_lists [V*S] | adj_lists_numnz [V] | out_mean [V]
#define ADJ_OFF 0
#define ATT_OFF (VERT_NUM * NUM_SAMPLES)
#define NNZ_OFF (2 * VERT_NUM * NUM_SAMPLES)
#define MEAN_OFF (2 * VERT_NUM * NUM_SAMPLES + VERT_NUM)

__device__ __forceinline__ float bfbits2f(unsigned int bits16) {
    return __uint_as_float(bits16 << 16);
}

// Probe: is float storage f32 (1) or packed bf16 (0)?
__device__ __forceinline__ int probe_isf32(const void* p) {
    const unsigned int* fu = (const unsigned int*)p;
    int cnt = 0;
    for (int i = 0; i < 64; ++i) {
        const unsigned int w = fu[i];
        const unsigned int e2 = (w >> 7) & 0xFFu;
        if (e2 >= 90u && e2 <= 140u && (w & 0xFFFFu) != 0u) ++cnt;
    }
    return (cnt >= 40) ? 0 : 1;
}

// Templated loads: no per-element select, vectorized when f32.
template <int ISF32>
__device__ __forceinline__ float ld1(const void* p, size_t idx) {
    if (ISF32) return ((const float*)p)[idx];
    return bfbits2f(((const unsigned short*)p)[idx]);
}

template <int ISF32>
__device__ __forceinline__ float4 load4(const void* p, size_t idx) {
    if (ISF32) {
        return *(const float4*)((const float*)p + idx);
    } else {
        const ushort4 u = *(const ushort4*)((const unsigned short*)p + idx);
        float4 v;
        v.x = bfbits2f(u.x); v.y = bfbits2f(u.y);
        v.z = bfbits2f(u.z); v.w = bfbits2f(u.w);
        return v;
    }
}

// ---------------------------------------------------------------------------
// Fused kernel body. fp64 accumulation of exact f32 products, f32
// materialization at each tensor boundary (l, out). All reduction ORDERS are
// kept identical to the previously-passing kernel (per-thread sequential
// k-loop; einsum 16-lane tree; epilogue (o0+o1)+tree16) so outputs are
// bit-identical — only the parallel decomposition changed.
//
// AL_s overlay: A-tile during matmul, L-tile during einsum.
// VPB=8 => 2048 blocks => 8 blocks/CU (grid was the occupancy cap at VPB=16).
// ---------------------------------------------------------------------------
template <int ISF32>
__device__ __forceinline__ void body(
    const int* __restrict__ adj_info,
    const void* __restrict__ features,
    const void* __restrict__ W,
    const void* __restrict__ bias,
    float* __restrict__ out,
    float (*AL_s)[NODE_DIM + 4],
    const int* s_ids,
    const int* s_ur,
    int (*s_adj)[NUM_SAMPLES],
    float (*s_out)[NUM_SAMPLES],
    int tid, int v0)
{
    // ---- stage gathered feature rows into LDS as f32 (coalesced float4) ----
    #pragma unroll
    for (int i = 0; i < 2; ++i) {
        const int idx = tid + i * 256;   // 0..511
        const int r = idx >> 6;          // 0..7 (uniform per wave)
        const int cg = (idx & 63) * 4;   // 0..252
        const float4 v = load4<ISF32>(features, (size_t)s_ids[r] * NODE_DIM + cg);
        *(float4*)&AL_s[r][cg] = v;
    }
    // gather adj samples: one per thread (8*32 = 256)
    {
        const int r = tid >> 5;
        const int s = tid & 31;
        s_adj[r][s] = adj_info[(size_t)s_ids[r] * MAX_DEGREE + s_ur[s]];
    }
    __syncthreads();

    // ---- l = A@W + b; thread = output column, fp64 accumulate ----
    double acc[VPB];
    {
        const int col = tid;
        #pragma unroll
        for (int g = 0; g < VPB; ++g) acc[g] = 0.0;
        for (int k = 0; k < NODE_DIM; k += 4) {
            const double w0 = (double)ld1<ISF32>(W, (size_t)(k + 0) * NODE_DIM + col);
            const double w1 = (double)ld1<ISF32>(W, (size_t)(k + 1) * NODE_DIM + col);
            const double w2 = (double)ld1<ISF32>(W, (size_t)(k + 2) * NODE_DIM + col);
            const double w3 = (double)ld1<ISF32>(W, (size_t)(k + 3) * NODE_DIM + col);
            #pragma unroll
            for (int g = 0; g < VPB; ++g) {
                const float4 a = *(const float4*)&AL_s[g][k];
                acc[g] = fma((double)a.x, w0, acc[g]);
                acc[g] = fma((double)a.y, w1, acc[g]);
                acc[g] = fma((double)a.z, w2, acc[g]);
                acc[g] = fma((double)a.w, w3, acc[g]);
            }
        }
    }
    // all A reads complete before L overwrites the same buffer
    __syncthreads();
    {
        const int col = tid;
        const double bv = (double)ld1<ISF32>(bias, col);
        #pragma unroll
        for (int g = 0; g < VPB; ++g) AL_s[g][col] = (float)(acc[g] + bv);
    }
    __syncthreads();

    // ---- einsum: 16-lane group per (vertex, half-samples) ----
    // Group q = tid>>4 (0..15): vertex g = q>>1, samples (q&1)*16 .. +15.
    // Per-sample dot order identical to previous kernel (tree-16).
    {
        const int q = tid >> 4;
        const int ln = tid & 15;
        const int g = q >> 1;
        const int so = (q & 1) * 16;
        const float4 Lv0 = *(const float4*)&AL_s[g][  0 + ln * 4];
        const float4 Lv1 = *(const float4*)&AL_s[g][ 64 + ln * 4];
        const float4 Lv2 = *(const float4*)&AL_s[g][128 + ln * 4];
        const float4 Lv3 = *(const float4*)&AL_s[g][192 + ln * 4];
        const int* adjq = s_adj[g];
        #pragma unroll 2
        for (int si = 0; si < 16; ++si) {
            const int s = so + si;
            const size_t base = (size_t)adjq[s] * NODE_DIM + ln * 4;
            const float4 f0 = load4<ISF32>(features, base +   0);
            const float4 f1 = load4<ISF32>(features, base +  64);
            const float4 f2 = load4<ISF32>(features, base + 128);
            const float4 f3 = load4<ISF32>(features, base + 192);
            double a = 0.0;
            a = fma((double)f0.x, (double)Lv0.x, a);
            a = fma((double)f0.y, (double)Lv0.y, a);
            a = fma((double)f0.z, (double)Lv0.z, a);
            a = fma((double)f0.w, (double)Lv0.w, a);
            a = fma((double)f1.x, (double)Lv1.x, a);
            a = fma((double)f1.y, (double)Lv1.y, a);
            a = fma((double)f1.z, (double)Lv1.z, a);
            a = fma((double)f1.w, (double)Lv1.w, a);
            a = fma((double)f2.x, (double)Lv2.x, a);
            a = fma((double)f2.y, (double)Lv2.y, a);
            a = fma((double)f2.z, (double)Lv2.z, a);
            a = fma((double)f2.w, (double)Lv2.w, a);
            a = fma((double)f3.x, (double)Lv3.x, a);
            a = fma((double)f3.y, (double)Lv3.y, a);
            a = fma((double)f3.z, (double)Lv3.z, a);
            a = fma((double)f3.w, (double)Lv3.w, a);
            // 16-lane tree reduce (fp64) — same order as before
            a += __shfl_xor(a, 8);
            a += __shfl_xor(a, 4);
            a += __shfl_xor(a, 2);
            a += __shfl_xor(a, 1);
            if (ln == 0) s_out[g][s] = (float)a;   // f32 materialization
        }
    }
    __syncthreads();

    // ---- epilogue: 16 lanes per vertex, 2 samples per lane (tid < 128) ----
    // Identical reduction order to the previously-passing kernel.
    if (tid < VPB * 16) {
        const int q = tid >> 4;
        const int ln = tid & 15;
        const int v = v0 + q;
        const float o0 = fmaxf(s_out[q][ln], 0.0f);
        const float o1 = fmaxf(s_out[q][ln + 16], 0.0f);
        double ss = (double)o0 + (double)o1;
        ss += __shfl_xor(ss, 8);
        ss += __shfl_xor(ss, 4);
        ss += __shfl_xor(ss, 2);
        ss += __shfl_xor(ss, 1);
        const float mean = (float)(ss * (1.0 / 32.0));
        const float thr = 0.5f * mean;
        const int n0 = s_adj[q][ln];
        const int n1 = s_adj[q][ln + 16];
        const bool c0 = (n0 == SENTINEL) || (o0 > thr);
        const bool c1 = (n1 == SENTINEL) || (o1 > thr);
        const size_t ob = (size_t)v * NUM_SAMPLES;
        out[ADJ_OFF + ob + ln]      = c0 ? (float)SENTINEL : (float)n0;
        out[ADJ_OFF + ob + ln + 16] = c1 ? (float)SENTINEL : (float)n1;
        out[ATT_OFF + ob + ln]      = 1.0f;
        out[ATT_OFF + ob + ln + 16] = 1.0f;
        int nz = (c0 ? 0 : 1) + (c1 ? 0 : 1);
        nz += __shfl_xor(nz, 8);
        nz += __shfl_xor(nz, 4);
        nz += __shfl_xor(nz, 2);
        nz += __shfl_xor(nz, 1);
        if (ln == 0) {
            out[NNZ_OFF + v] = (float)nz;
            out[MEAN_OFF + v] = mean;
        }
    }
}

__global__ __launch_bounds__(256, 8)
void FastMLNeighborSampler___9337258901923_kernel(
    const int* ids,
    const int* unif_rand,
    const int* adj_info,
    const void* features_raw,
    const void* W_raw,
    const void* bias_raw,
    float* out) {
    __shared__ float AL_s[VPB][NODE_DIM + 4];   // A-tile, then L-tile (overlay)
    __shared__ int s_ids[VPB];
    __shared__ int s_ur[NUM_SAMPLES];
    __shared__ int s_adj[VPB][NUM_SAMPLES];
    __shared__ float s_out[VPB][NUM_SAMPLES];
    __shared__ int s_isf32;

    const int tid = threadIdx.x;
    const int v0 = blockIdx.x * VPB;

    if (tid == 0) s_isf32 = probe_isf32(features_raw);
    if (tid < VPB) {
        s_ids[tid] = ids[v0 + tid];
    } else if (tid < VPB + NUM_SAMPLES) {
        s_ur[tid - VPB] = unif_rand[tid - VPB];
    }
    __syncthreads();

    if (s_isf32) {
        body<1>(adj_info, features_raw, W_raw, bias_raw, out,
                AL_s, s_ids, s_ur, s_adj, s_out, tid, v0);
    } else {
        body<0>(adj_info, features_raw, W_raw, bias_raw, out,
                AL_s, s_ids, s_ur, s_adj, s_out, tid, v0);
    }
}

extern "C" void kernel_launch(void* const* d_in, const int* in_sizes, int n_in,
                              void* d_out, int out_size, void* d_ws, size_t ws_size,
                              hipStream_t stream) {
    const int* ids = nullptr;
    const int* unif_rand = nullptr;
    const int* adj_info = nullptr;
    const void* features = nullptr;
    const void* W = nullptr;
    const void* bias = nullptr;
    for (int i = 0; i < n_in; ++i) {
        switch (in_sizes[i]) {
            case VERT_NUM:               ids       = (const int*)d_in[i]; break;
            case NUM_SAMPLES:            unif_rand = (const int*)d_in[i]; break;
            case NUM_NODES * MAX_DEGREE: adj_info  = (const int*)d_in[i]; break;
            case NUM_NODES * NODE_DIM:   features  = (const void*)d_in[i]; break;
            case NODE_DIM * NODE_DIM:    W         = (const void*)d_in[i]; break;
            case NODE_DIM:               bias      = (const void*)d_in[i]; break;
            default: break;
        }
    }
    if (!ids || !unif_rand || !adj_info || !features || !W || !bias) {
        ids       = (const int*)d_in[0];
        unif_rand = (const int*)d_in[1];
        adj_info  = (const int*)d_in[2];
        features  = (const void*)d_in[3];
        W         = (const void*)d_in[4];
        bias      = (const void*)d_in[5];
    }
    float* out = (float*)d_out;

    FastMLNeighborSampler___9337258901923_kernel<<<NBLK, 256, 0, stream>>>(
        ids, unif_rand, adj_info, features, W, bias, out);
}

// Round 4
// 270.844 us; speedup vs baseline: 1.9996x; 1.2844x over previous
//
#include <hip/hip_runtime.h>

// Problem constants (from reference)
#define NUM_NODES 100000
#define MAX_DEGREE 128
#define NODE_DIM 256
#define VERT_NUM 16384
#define NUM_SAMPLES 32
#define SENTINEL (NUM_NODES - 1)

#define VPB 8                    // vertices per block
#define NBLK (VERT_NUM / VPB)    // 2048 blocks = 8 blocks/CU on 256 CUs

// Output layout (FLOAT32 elements), concatenated in reference return order:
// adj_out [V*S] | att_lists [V*S] | adj_lists_numnz [V] | out_mean [V]
#define ADJ_OFF 0
#define ATT_OFF (VERT_NUM * NUM_SAMPLES)
#define NNZ_OFF (2 * VERT_NUM * NUM_SAMPLES)
#define MEAN_OFF (2 * VERT_NUM * NUM_SAMPLES + VERT_NUM)

__device__ __forceinline__ float bfbits2f(unsigned int bits16) {
    return __uint_as_float(bits16 << 16);
}

// Probe: is float storage f32 (1) or packed bf16 (0)?
__device__ __forceinline__ int probe_isf32(const void* p) {
    const unsigned int* fu = (const unsigned int*)p;
    int cnt = 0;
    for (int i = 0; i < 64; ++i) {
        const unsigned int w = fu[i];
        const unsigned int e2 = (w >> 7) & 0xFFu;
        if (e2 >= 90u && e2 <= 140u && (w & 0xFFFFu) != 0u) ++cnt;
    }
    return (cnt >= 40) ? 0 : 1;
}

// Templated loads: no per-element select, vectorized when f32.
template <int ISF32>
__device__ __forceinline__ float ld1(const void* p, size_t idx) {
    if (ISF32) return ((const float*)p)[idx];
    return bfbits2f(((const unsigned short*)p)[idx]);
}

template <int ISF32>
__device__ __forceinline__ float4 load4(const void* p, size_t idx) {
    if (ISF32) {
        return *(const float4*)((const float*)p + idx);
    } else {
        const ushort4 u = *(const ushort4*)((const unsigned short*)p + idx);
        float4 v;
        v.x = bfbits2f(u.x); v.y = bfbits2f(u.y);
        v.z = bfbits2f(u.z); v.w = bfbits2f(u.w);
        return v;
    }
}

// ---------------------------------------------------------------------------
// Fused kernel body. fp64 accumulation of exact f32 products, f32
// materialization at each tensor boundary (l, out). All arithmetic ORDERS
// are identical to the previously-passing kernel — R4 only adds explicit
// software pipelining (register prefetch) for latency hiding:
//   * einsum: 2-deep sample pipeline (fA/fB buffers, static unroll)
//   * matmul: next-k W quad prefetched into f32 regs during current FMAs
// ---------------------------------------------------------------------------
template <int ISF32>
__device__ __forceinline__ void body(
    const int* __restrict__ adj_info,
    const void* __restrict__ features,
    const void* __restrict__ W,
    const void* __restrict__ bias,
    float* __restrict__ out,
    float (*AL_s)[NODE_DIM + 4],
    const int* s_ids,
    const int* s_ur,
    int (*s_adj)[NUM_SAMPLES],
    float (*s_out)[NUM_SAMPLES],
    int tid, int v0)
{
    // ---- stage gathered feature rows into LDS as f32 (coalesced float4) ----
    #pragma unroll
    for (int i = 0; i < 2; ++i) {
        const int idx = tid + i * 256;   // 0..511
        const int r = idx >> 6;          // 0..7 (uniform per wave)
        const int cg = (idx & 63) * 4;   // 0..252
        const float4 v = load4<ISF32>(features, (size_t)s_ids[r] * NODE_DIM + cg);
        *(float4*)&AL_s[r][cg] = v;
    }
    // gather adj samples: one per thread (8*32 = 256)
    {
        const int r = tid >> 5;
        const int s = tid & 31;
        s_adj[r][s] = adj_info[(size_t)s_ids[r] * MAX_DEGREE + s_ur[s]];
    }
    __syncthreads();

    // ---- l = A@W + b; thread = output column, fp64 accumulate ----
    double acc[VPB];
    {
        const int col = tid;
        #pragma unroll
        for (int g = 0; g < VPB; ++g) acc[g] = 0.0;
        // prefetch k=0 W quad
        float wn0 = ld1<ISF32>(W, (size_t)0 * NODE_DIM + col);
        float wn1 = ld1<ISF32>(W, (size_t)1 * NODE_DIM + col);
        float wn2 = ld1<ISF32>(W, (size_t)2 * NODE_DIM + col);
        float wn3 = ld1<ISF32>(W, (size_t)3 * NODE_DIM + col);
        #pragma unroll 2
        for (int k = 0; k < NODE_DIM; k += 4) {
            const double w0 = (double)wn0;
            const double w1 = (double)wn1;
            const double w2 = (double)wn2;
            const double w3 = (double)wn3;
            if (k + 4 < NODE_DIM) {   // prefetch next quad during FMAs
                wn0 = ld1<ISF32>(W, (size_t)(k + 4) * NODE_DIM + col);
                wn1 = ld1<ISF32>(W, (size_t)(k + 5) * NODE_DIM + col);
                wn2 = ld1<ISF32>(W, (size_t)(k + 6) * NODE_DIM + col);
                wn3 = ld1<ISF32>(W, (size_t)(k + 7) * NODE_DIM + col);
            }
            #pragma unroll
            for (int g = 0; g < VPB; ++g) {
                const float4 a = *(const float4*)&AL_s[g][k];
                acc[g] = fma((double)a.x, w0, acc[g]);
                acc[g] = fma((double)a.y, w1, acc[g]);
                acc[g] = fma((double)a.z, w2, acc[g]);
                acc[g] = fma((double)a.w, w3, acc[g]);
            }
        }
    }
    // all A reads complete before L overwrites the same buffer
    __syncthreads();
    {
        const int col = tid;
        const double bv = (double)ld1<ISF32>(bias, col);
        #pragma unroll
        for (int g = 0; g < VPB; ++g) AL_s[g][col] = (float)(acc[g] + bv);
    }
    __syncthreads();

    // ---- einsum: 16-lane group per (vertex, half-samples), pipelined ----
    // Group q = tid>>4 (0..15): vertex g = q>>1, samples (q&1)*16 .. +15.
    // Per-sample FMA order + tree-16 reduce identical to passing kernel.
    {
        const int q = tid >> 4;
        const int ln = tid & 15;
        const int g = q >> 1;
        const int so = (q & 1) * 16;
        const int ln4 = ln * 4;
        const float4 Lv0 = *(const float4*)&AL_s[g][  0 + ln4];
        const float4 Lv1 = *(const float4*)&AL_s[g][ 64 + ln4];
        const float4 Lv2 = *(const float4*)&AL_s[g][128 + ln4];
        const float4 Lv3 = *(const float4*)&AL_s[g][192 + ln4];
        const int* adjq = s_adj[g];

        float4 fA0, fA1, fA2, fA3, fB0, fB1, fB2, fB3;

#define EIN_LOAD(B0, B1, B2, B3, SIDX) do {                                 \
            const size_t b_ = (size_t)adjq[(SIDX)] * NODE_DIM + ln4;        \
            B0 = load4<ISF32>(features, b_ +   0);                          \
            B1 = load4<ISF32>(features, b_ +  64);                          \
            B2 = load4<ISF32>(features, b_ + 128);                          \
            B3 = load4<ISF32>(features, b_ + 192);                          \
        } while (0)

#define EIN_COMPUTE(B0, B1, B2, B3, SIDX) do {                              \
            double a_ = 0.0;                                                \
            a_ = fma((double)B0.x, (double)Lv0.x, a_);                      \
            a_ = fma((double)B0.y, (double)Lv0.y, a_);                      \
            a_ = fma((double)B0.z, (double)Lv0.z, a_);                      \
            a_ = fma((double)B0.w, (double)Lv0.w, a_);                      \
            a_ = fma((double)B1.x, (double)Lv1.x, a_);                      \
            a_ = fma((double)B1.y, (double)Lv1.y, a_);                      \
            a_ = fma((double)B1.z, (double)Lv1.z, a_);                      \
            a_ = fma((double)B1.w, (double)Lv1.w, a_);                      \
            a_ = fma((double)B2.x, (double)Lv2.x, a_);                      \
            a_ = fma((double)B2.y, (double)Lv2.y, a_);                      \
            a_ = fma((double)B2.z, (double)Lv2.z, a_);                      \
            a_ = fma((double)B2.w, (double)Lv2.w, a_);                      \
            a_ = fma((double)B3.x, (double)Lv3.x, a_);                      \
            a_ = fma((double)B3.y, (double)Lv3.y, a_);                      \
            a_ = fma((double)B3.z, (double)Lv3.z, a_);                      \
            a_ = fma((double)B3.w, (double)Lv3.w, a_);                      \
            a_ += __shfl_xor(a_, 8);                                        \
            a_ += __shfl_xor(a_, 4);                                        \
            a_ += __shfl_xor(a_, 2);                                        \
            a_ += __shfl_xor(a_, 1);                                        \
            if (ln == 0) s_out[g][(SIDX)] = (float)a_;                      \
        } while (0)

        EIN_LOAD(fA0, fA1, fA2, fA3, so + 0);
        #pragma unroll
        for (int si = 0; si < 16; si += 2) {
            EIN_LOAD(fB0, fB1, fB2, fB3, so + si + 1);
            EIN_COMPUTE(fA0, fA1, fA2, fA3, so + si);
            if (si + 2 < 16) EIN_LOAD(fA0, fA1, fA2, fA3, so + si + 2);
            EIN_COMPUTE(fB0, fB1, fB2, fB3, so + si + 1);
        }
#undef EIN_LOAD
#undef EIN_COMPUTE
    }
    __syncthreads();

    // ---- epilogue: 16 lanes per vertex, 2 samples per lane (tid < 128) ----
    if (tid < VPB * 16) {
        const int q = tid >> 4;
        const int ln = tid & 15;
        const int v = v0 + q;
        const float o0 = fmaxf(s_out[q][ln], 0.0f);
        const float o1 = fmaxf(s_out[q][ln + 16], 0.0f);
        double ss = (double)o0 + (double)o1;
        ss += __shfl_xor(ss, 8);
        ss += __shfl_xor(ss, 4);
        ss += __shfl_xor(ss, 2);
        ss += __shfl_xor(ss, 1);
        const float mean = (float)(ss * (1.0 / 32.0));
        const float thr = 0.5f * mean;
        const int n0 = s_adj[q][ln];
        const int n1 = s_adj[q][ln + 16];
        const bool c0 = (n0 == SENTINEL) || (o0 > thr);
        const bool c1 = (n1 == SENTINEL) || (o1 > thr);
        const size_t ob = (size_t)v * NUM_SAMPLES;
        out[ADJ_OFF + ob + ln]      = c0 ? (float)SENTINEL : (float)n0;
        out[ADJ_OFF + ob + ln + 16] = c1 ? (float)SENTINEL : (float)n1;
        out[ATT_OFF + ob + ln]      = 1.0f;
        out[ATT_OFF + ob + ln + 16] = 1.0f;
        int nz = (c0 ? 0 : 1) + (c1 ? 0 : 1);
        nz += __shfl_xor(nz, 8);
        nz += __shfl_xor(nz, 4);
        nz += __shfl_xor(nz, 2);
        nz += __shfl_xor(nz, 1);
        if (ln == 0) {
            out[NNZ_OFF + v] = (float)nz;
            out[MEAN_OFF + v] = mean;
        }
    }
}

__global__ __launch_bounds__(256, 6)
void FastMLNeighborSampler___9337258901923_kernel(
    const int* ids,
    const int* unif_rand,
    const int* adj_info,
    const void* features_raw,
    const void* W_raw,
    const void* bias_raw,
    float* out) {
    __shared__ float AL_s[VPB][NODE_DIM + 4];   // A-tile, then L-tile (overlay)
    __shared__ int s_ids[VPB];
    __shared__ int s_ur[NUM_SAMPLES];
    __shared__ int s_adj[VPB][NUM_SAMPLES];
    __shared__ float s_out[VPB][NUM_SAMPLES];
    __shared__ int s_isf32;

    const int tid = threadIdx.x;
    const int v0 = blockIdx.x * VPB;

    if (tid == 0) s_isf32 = probe_isf32(features_raw);
    if (tid < VPB) {
        s_ids[tid] = ids[v0 + tid];
    } else if (tid < VPB + NUM_SAMPLES) {
        s_ur[tid - VPB] = unif_rand[tid - VPB];
    }
    __syncthreads();

    if (s_isf32) {
        body<1>(adj_info, features_raw, W_raw, bias_raw, out,
                AL_s, s_ids, s_ur, s_adj, s_out, tid, v0);
    } else {
        body<0>(adj_info, features_raw, W_raw, bias_raw, out,
                AL_s, s_ids, s_ur, s_adj, s_out, tid, v0);
    }
}

extern "C" void kernel_launch(void* const* d_in, const int* in_sizes, int n_in,
                              void* d_out, int out_size, void* d_ws, size_t ws_size,
                              hipStream_t stream) {
    const int* ids = nullptr;
    const int* unif_rand = nullptr;
    const int* adj_info = nullptr;
    const void* features = nullptr;
    const void* W = nullptr;
    const void* bias = nullptr;
    for (int i = 0; i < n_in; ++i) {
        switch (in_sizes[i]) {
            case VERT_NUM:               ids       = (const int*)d_in[i]; break;
            case NUM_SAMPLES:            unif_rand = (const int*)d_in[i]; break;
            case NUM_NODES * MAX_DEGREE: adj_info  = (const int*)d_in[i]; break;
            case NUM_NODES * NODE_DIM:   features  = (const void*)d_in[i]; break;
            case NODE_DIM * NODE_DIM:    W         = (const void*)d_in[i]; break;
            case NODE_DIM:               bias      = (const void*)d_in[i]; break;
            default: break;
        }
    }
    if (!ids || !unif_rand || !adj_info || !features || !W || !bias) {
        ids       = (const int*)d_in[0];
        unif_rand = (const int*)d_in[1];
        adj_info  = (const int*)d_in[2];
        features  = (const void*)d_in[3];
        W         = (const void*)d_in[4];
        bias      = (const void*)d_in[5];
    }
    float* out = (float*)d_out;

    FastMLNeighborSampler___9337258901923_kernel<<<NBLK, 256, 0, stream>>>(
        ids, unif_rand, adj_info, features, W, bias, out);
}